// Round 8
// baseline (17735.670 us; speedup 1.0000x reference)
//
#include <hip/hip_runtime.h>
#include <stdint.h>

#define NN 2048
#define TT 365
#define DD 16
#define HH 64
#define NBLK 256
#define NTHR 512
#define SMEM_BYTES 122880

typedef __attribute__((ext_vector_type(8))) short bf16x8;
typedef __attribute__((ext_vector_type(4))) float f32x4;

__device__ __forceinline__ unsigned short f2bf(float f) {
  union { float f; uint32_t u; } z; z.f = f;
  uint32_t r = z.u + 0x7fffu + ((z.u >> 16) & 1u);
  return (unsigned short)(r >> 16);
}
__device__ __forceinline__ float lo16(uint32_t u) {
  union { uint32_t u; float f; } z; z.u = u << 16; return z.f;
}
__device__ __forceinline__ float hi16(uint32_t u) {
  union { uint32_t u; float f; } z; z.u = u & 0xffff0000u; return z.f;
}
__device__ __forceinline__ float sigmoid_(float x) { return 1.f / (1.f + __expf(-x)); }
__device__ __forceinline__ float tanh_(float x) {
  float ax = fabsf(x);
  float e = __expf(-2.f * ax);
  float r = (1.f - e) / (1.f + e);
  return x < 0.f ? -r : r;
}

// Persistent kernel (R2 skeleton + fp32-out fix). 256 blocks x 512 thr, 8 rows/block.
// Per step: fp32 phase A (bf16 weights in LDS, shfl-broadcast h/x, gates in regs)
// -> publish q bf16 transposed (double-buffered) -> device barrier (monotonic)
// -> phase B: MFMA A@q (A-frags from LDS, B-frags from global qT) -> update -> out.
__global__ __launch_bounds__(NTHR) void rgcn_persist(
    const float* __restrict__ X, const float* __restrict__ Af,
    const float* __restrict__ Wih, const float* __restrict__ Whh,
    const float* __restrict__ Bias, const float* __restrict__ Wq,
    const float* __restrict__ Bq, const float* __restrict__ Wd,
    const float* __restrict__ Bd, float* __restrict__ Out,
    unsigned short* __restrict__ qT0, unsigned short* __restrict__ qT1,
    unsigned* __restrict__ bar)
{
  extern __shared__ __align__(16) char smem[];
  uint2*          whh2  = (uint2*)smem;                      // [64][64] bf16x4  32768
  uint2*          wih2  = (uint2*)(smem + 32768);            // [16][64] bf16x4   8192
  uint32_t*       wqp   = (uint32_t*)(smem + 40960);         // [32][64] bf16x2   8192
  unsigned short* afrag = (unsigned short*)(smem + 49152);   // [64 kc][64 lane][8] 65536
  f32x4*          sh_part = (f32x4*)(smem + 114688);         // [8][64] f32x4     8192

  const int tid = threadIdx.x;
  const int w = tid >> 6;        // wave 0..7 == local row
  const int c = tid & 63;        // lane
  const int base = blockIdx.x * 8;

  // ---- one-time: pack weights bf16 into LDS ----
  for (int idx = tid; idx < 64 * 64; idx += NTHR) {
    int k = idx >> 6, cc = idx & 63;
    uint2 p;
    p.x = (uint32_t)f2bf(Whh[k * 256 + cc])       | ((uint32_t)f2bf(Whh[k * 256 + 64 + cc]) << 16);
    p.y = (uint32_t)f2bf(Whh[k * 256 + 128 + cc]) | ((uint32_t)f2bf(Whh[k * 256 + 192 + cc]) << 16);
    whh2[idx] = p;
  }
  for (int idx = tid; idx < 16 * 64; idx += NTHR) {
    int k = idx >> 6, cc = idx & 63;
    uint2 p;
    p.x = (uint32_t)f2bf(Wih[k * 256 + cc])       | ((uint32_t)f2bf(Wih[k * 256 + 64 + cc]) << 16);
    p.y = (uint32_t)f2bf(Wih[k * 256 + 128 + cc]) | ((uint32_t)f2bf(Wih[k * 256 + 192 + cc]) << 16);
    wih2[idx] = p;
  }
  for (int idx = tid; idx < 32 * 64; idx += NTHR) {
    int kk = idx >> 6, cc = idx & 63;
    wqp[idx] = (uint32_t)f2bf(Wq[(2 * kk) * 64 + cc]) |
               ((uint32_t)f2bf(Wq[(2 * kk + 1) * 64 + cc]) << 16);
  }
  // ---- one-time: own 8 A-rows -> bf16 MFMA A-fragment layout in LDS ----
  // lane l=(quad*16+m) reads afrag[kc*512 + l*8 .. +7] = A[base+(m&7)][kc*32+quad*8 ..]
  for (int i = tid; i < 8 * NN; i += NTHR) {
    int r = i >> 11, k = i & (NN - 1);
    unsigned short v = f2bf(Af[(size_t)(base + r) * NN + k]);
    int kc = k >> 5, q = (k >> 3) & 3, e = k & 7;
    afrag[kc * 512 + (q * 16 + r) * 8 + e] = v;
    afrag[kc * 512 + (q * 16 + r + 8) * 8 + e] = v;   // duplicate rows 8..15
  }
  __syncthreads();

  const float b_i = Bias[c], b_f = Bias[64 + c], b_g = Bias[128 + c], b_o = Bias[192 + c];
  const float bqc = Bq[c], wdc = Wd[c], bdc = Bd[0];
  const int m = c & 15, quad = c >> 4;
  const int nt = w & 3, kh = w >> 2;           // phase B: col tile / K half
  const unsigned short* afp = afrag + (kh * 32) * 512 + c * 8;

  float creg = 0.f, hreg = 0.f;
  float gi, gf, gg, go;
  unsigned target = NBLK;

  auto phaseA = [&](float xreg, float hv, int parity) {
    float ai = b_i, af_ = b_f, ag = b_g, ao = b_o, aq = bqc;
    #pragma unroll
    for (int k = 0; k < 16; ++k) {
      float xv = __shfl(xreg, k, 64);
      uint2 p = wih2[k * 64 + c];
      ai += xv * lo16(p.x); af_ += xv * hi16(p.x);
      ag += xv * lo16(p.y); ao += xv * hi16(p.y);
    }
    #pragma unroll 8
    for (int kk = 0; kk < 32; ++kk) {
      float h0 = __shfl(hv, 2 * kk, 64);
      float h1 = __shfl(hv, 2 * kk + 1, 64);
      uint2 p0 = whh2[(2 * kk) * 64 + c];
      uint2 p1 = whh2[(2 * kk + 1) * 64 + c];
      uint32_t uq = wqp[kk * 64 + c];
      ai  += h0 * lo16(p0.x) + h1 * lo16(p1.x);
      af_ += h0 * hi16(p0.x) + h1 * hi16(p1.x);
      ag  += h0 * lo16(p0.y) + h1 * lo16(p1.y);
      ao  += h0 * hi16(p0.y) + h1 * hi16(p1.y);
      aq  += h0 * lo16(uq)  + h1 * hi16(uq);
    }
    gi = sigmoid_(ai); gf = sigmoid_(af_); gg = tanh_(ag); go = sigmoid_(ao);
    float qv = tanh_(aq);
    unsigned short* qTw = parity ? qT1 : qT0;
    qTw[(size_t)c * NN + base + w] = f2bf(qv);   // q transposed, bf16
  };

  // bootstrap: phase A(0) with h = 0
  {
    float xreg = (c < 16) ? X[(size_t)(base + w) * (TT * DD) + c] : 0.f;
    phaseA(xreg, 0.f, 0);
  }

  for (int t = 0; t < TT; ++t) {
    // prefetch x(t+1) early (hidden under barrier + phase B)
    float xnext = 0.f;
    if (c < 16 && t < TT - 1)
      xnext = X[(size_t)(base + w) * (TT * DD) + (t + 1) * DD + c];

    // ---- device-wide barrier ----
    __syncthreads();                    // drain qT stores of all waves
    if (tid == 0) {
      __hip_atomic_fetch_add(bar, 1u, __ATOMIC_RELEASE, __HIP_MEMORY_SCOPE_AGENT);
      while (__hip_atomic_load(bar, __ATOMIC_RELAXED, __HIP_MEMORY_SCOPE_AGENT) < target)
        __builtin_amdgcn_s_sleep(2);
    }
    __syncthreads();
    __builtin_amdgcn_fence(__ATOMIC_ACQUIRE, "agent");
    target += NBLK;

    // ---- phase B: Aq = A @ q_t (MFMA), wave (nt, kh) ----
    const unsigned short* qTr = (t & 1) ? qT1 : qT0;
    const unsigned short* qrow = qTr + (size_t)(nt * 16 + m) * NN + kh * 1024 + quad * 8;
    f32x4 acc = {0.f, 0.f, 0.f, 0.f};
    #pragma unroll 8
    for (int ch = 0; ch < 32; ++ch) {
      bf16x8 av = *(const bf16x8*)(afp + ch * 512);
      bf16x8 bv = *(const bf16x8*)(qrow + ch * 32);
      acc = __builtin_amdgcn_mfma_f32_16x16x32_bf16(av, bv, acc, 0, 0, 0);
    }
    sh_part[w * 64 + c] = acc;
    __syncthreads();

    // D layout: col=lane&15, row=(lane>>4)*4+reg. Row w (<8), col c: sum 2 K halves.
    const float* pf = (const float*)sh_part;
    int pidx = (((c >> 4) * 64) + ((w >> 2) * 16 + (c & 15))) * 4 + (w & 3);
    float aqv = pf[pidx] + pf[pidx + 1024];

    // ---- update (gates/c in registers) + fused output projection ----
    creg = gf * (creg + aqv) + gi * gg;
    hreg = go * tanh_(creg);
    float red = hreg * wdc;
    #pragma unroll
    for (int off = 32; off; off >>= 1) red += __shfl_xor(red, off);
    if (c == 0) Out[(size_t)(base + w) * TT + t] = red + bdc;   // fp32 store

    // ---- phase A(t+1) ----
    if (t < TT - 1) phaseA(xnext, hreg, (t + 1) & 1);
    // sh_part WAR for t+1 is ordered by the next device barrier + __syncthreads
  }
}

extern "C" void kernel_launch(void* const* d_in, const int* in_sizes, int n_in,
                              void* d_out, int out_size, void* d_ws, size_t ws_size,
                              hipStream_t stream) {
  const float* X    = (const float*)d_in[0];
  const float* Af   = (const float*)d_in[1];
  const float* Wih  = (const float*)d_in[2];
  const float* Whh  = (const float*)d_in[3];
  const float* Bias = (const float*)d_in[4];
  const float* Wq   = (const float*)d_in[5];
  const float* Bq   = (const float*)d_in[6];
  const float* Wd   = (const float*)d_in[7];
  const float* Bd   = (const float*)d_in[8];
  float* Out = (float*)d_out;

  char* ws = (char*)d_ws;
  unsigned* bar = (unsigned*)ws;                               // @0
  unsigned short* qT0 = (unsigned short*)(ws + 1024);          // 64*2048 bf16 = 256 KB
  unsigned short* qT1 = (unsigned short*)(ws + 1024 + 262144);

  hipFuncSetAttribute((const void*)rgcn_persist,
                      hipFuncAttributeMaxDynamicSharedMemorySize, SMEM_BYTES);
  hipMemsetAsync(ws, 0, 256, stream);                          // zero barrier counter
  hipLaunchKernelGGL(rgcn_persist, dim3(NBLK), dim3(NTHR), SMEM_BYTES, stream,
                     X, Af, Wih, Whh, Bias, Wq, Bq, Wd, Bd, Out, qT0, qT1, bar);
}

// Round 9
// 9705.310 us; speedup vs baseline: 1.8274x; 1.8274x over previous
//
#include <hip/hip_runtime.h>
#include <stdint.h>

#define NN 2048
#define TT 365
#define DD 16
#define HH 64
#define NBLK 128      // 16 rows per block, 1 block/CU (LDS-bound), all co-resident
#define NTHR 1024     // 16 waves; wave w = row w in phase A / (nt,kh) tile in phase B
#define SMEM_BYTES 133120

typedef __attribute__((ext_vector_type(8))) short bf16x8;
typedef __attribute__((ext_vector_type(4))) float f32x4;

__device__ __forceinline__ unsigned short f2bf(float f) {
  union { float f; uint32_t u; } z; z.f = f;
  uint32_t r = z.u + 0x7fffu + ((z.u >> 16) & 1u);
  return (unsigned short)(r >> 16);
}
__device__ __forceinline__ float lo16(uint32_t u) {
  union { uint32_t u; float f; } z; z.u = u << 16; return z.f;
}
__device__ __forceinline__ float hi16(uint32_t u) {
  union { uint32_t u; float f; } z; z.u = u & 0xffff0000u; return z.f;
}
__device__ __forceinline__ float sigmoid_(float x) { return 1.f / (1.f + __expf(-x)); }
__device__ __forceinline__ float tanh_(float x) {
  float ax = fabsf(x);
  float e = __expf(-2.f * ax);
  float r = (1.f - e) / (1.f + e);
  return x < 0.f ? -r : r;
}

// Persistent kernel, FENCE-FREE sync: all cross-block data (qP, flags) uses
// device-coherent relaxed atomics (sc1: acked at coherence point, bypasses L2)
// -> no buffer_wbl2/buffer_inv on the 365-step critical path.
// qP = q transposed [64 cols][1024 u32 (2 bf16 nodes each)], double-buffered.
// flags[blk] = #q-publications by blk; consumers of step t wait all >= t+1.
__global__ __launch_bounds__(NTHR) void rgcn_persist(
    const float* __restrict__ X, const float* __restrict__ Af,
    const float* __restrict__ Wih, const float* __restrict__ Whh,
    const float* __restrict__ Bias, const float* __restrict__ Wq,
    const float* __restrict__ Bq, const float* __restrict__ Wd,
    const float* __restrict__ Bd, float* __restrict__ Out,
    uint32_t* qP0, uint32_t* qP1, uint32_t* flags)
{
  extern __shared__ __align__(16) char smem[];
  uint2*          whh2    = (uint2*)smem;                      // [64][64] bf16x4   32768
  uint2*          wih2    = (uint2*)(smem + 32768);            // [16][64] bf16x4    8192
  uint32_t*       wqp     = (uint32_t*)(smem + 40960);         // [32][64] bf16x2    8192
  unsigned short* afrag   = (unsigned short*)(smem + 49152);   // [64 kc][64 ln][8]  65536
  f32x4*          sh_part = (f32x4*)(smem + 114688);           // [16][64] f32x4     16384
  unsigned short* sh_q    = (unsigned short*)(smem + 131072);  // [16][64] bf16       2048

  const int tid = threadIdx.x;
  const int w = tid >> 6;        // wave 0..15
  const int c = tid & 63;        // lane
  const int base = blockIdx.x * 16;

  // ---- one-time: pack weights bf16 into LDS ----
  for (int idx = tid; idx < 64 * 64; idx += NTHR) {
    int k = idx >> 6, cc = idx & 63;
    uint2 p;
    p.x = (uint32_t)f2bf(Whh[k * 256 + cc])       | ((uint32_t)f2bf(Whh[k * 256 + 64 + cc]) << 16);
    p.y = (uint32_t)f2bf(Whh[k * 256 + 128 + cc]) | ((uint32_t)f2bf(Whh[k * 256 + 192 + cc]) << 16);
    whh2[idx] = p;
  }
  for (int idx = tid; idx < 16 * 64; idx += NTHR) {
    int k = idx >> 6, cc = idx & 63;
    uint2 p;
    p.x = (uint32_t)f2bf(Wih[k * 256 + cc])       | ((uint32_t)f2bf(Wih[k * 256 + 64 + cc]) << 16);
    p.y = (uint32_t)f2bf(Wih[k * 256 + 128 + cc]) | ((uint32_t)f2bf(Wih[k * 256 + 192 + cc]) << 16);
    wih2[idx] = p;
  }
  for (int idx = tid; idx < 32 * 64; idx += NTHR) {
    int kk = idx >> 6, cc = idx & 63;
    wqp[idx] = (uint32_t)f2bf(Wq[(2 * kk) * 64 + cc]) |
               ((uint32_t)f2bf(Wq[(2 * kk + 1) * 64 + cc]) << 16);
  }
  // ---- one-time: own 16 A-rows -> bf16 MFMA A-fragment layout (no duplication) ----
  for (int i = tid; i < 16 * NN; i += NTHR) {
    int r = i >> 11, k = i & (NN - 1);
    unsigned short v = f2bf(Af[(size_t)(base + r) * NN + k]);
    afrag[(k >> 5) * 512 + (((k >> 3) & 3) * 16 + r) * 8 + (k & 7)] = v;
  }
  __syncthreads();

  const float b_i = Bias[c], b_f = Bias[64 + c], b_g = Bias[128 + c], b_o = Bias[192 + c];
  const float bqc = Bq[c], wdc = Wd[c], bdc = Bd[0];
  const int m = c & 15, quad = c >> 4;
  const int nt = w & 3, kh = w >> 2;           // phase B: 16-col tile, 512-K quarter
  const unsigned short* afp = afrag + (kh * 16) * 512 + c * 8;

  float creg = 0.f, hreg = 0.f;
  float gi, gf, gg, go;

  auto phaseA = [&](float xreg, float hv) -> float {
    float ai = b_i, af_ = b_f, ag = b_g, ao = b_o, aq = bqc;
    #pragma unroll
    for (int k = 0; k < 16; ++k) {
      float xv = __shfl(xreg, k, 64);
      uint2 p = wih2[k * 64 + c];
      ai += xv * lo16(p.x); af_ += xv * hi16(p.x);
      ag += xv * lo16(p.y); ao += xv * hi16(p.y);
    }
    #pragma unroll 8
    for (int kk = 0; kk < 32; ++kk) {
      float h0 = __shfl(hv, 2 * kk, 64);
      float h1 = __shfl(hv, 2 * kk + 1, 64);
      uint2 p0 = whh2[(2 * kk) * 64 + c];
      uint2 p1 = whh2[(2 * kk + 1) * 64 + c];
      uint32_t uq = wqp[kk * 64 + c];
      ai  += h0 * lo16(p0.x) + h1 * lo16(p1.x);
      af_ += h0 * hi16(p0.x) + h1 * hi16(p1.x);
      ag  += h0 * lo16(p0.y) + h1 * lo16(p1.y);
      ao  += h0 * hi16(p0.y) + h1 * hi16(p1.y);
      aq  += h0 * lo16(uq)  + h1 * hi16(uq);
    }
    gi = sigmoid_(ai); gf = sigmoid_(af_); gg = tanh_(ag); go = sigmoid_(ao);
    return tanh_(aq);
  };

  auto publish = [&](float qv, uint32_t* qP, uint32_t flagval) {
    sh_q[w * 64 + c] = f2bf(qv);
    __syncthreads();
    if (tid < 512) {                       // 8 u32 (16 rows) per column
      int col = tid & 63, pr = tid >> 6;
      uint32_t v = (uint32_t)sh_q[(2 * pr) * 64 + col] |
                   ((uint32_t)sh_q[(2 * pr + 1) * 64 + col] << 16);
      __hip_atomic_store(&qP[(size_t)col * (NN / 2) + (base >> 1) + pr], v,
                         __ATOMIC_RELAXED, __HIP_MEMORY_SCOPE_AGENT);
    }
    __builtin_amdgcn_s_waitcnt(0);         // own sc1 stores acked at coherence point
    asm volatile("" ::: "memory");
    __syncthreads();                       // all storing waves drained
    if (tid == 0)
      __hip_atomic_store(&flags[blockIdx.x], flagval,
                         __ATOMIC_RELAXED, __HIP_MEMORY_SCOPE_AGENT);
  };

  // bootstrap: phase A(0) with h = 0, publish q_0 (flag=1)
  {
    float x0 = (c < 16) ? X[(size_t)(base + w) * (TT * DD) + c] : 0.f;
    float qv = phaseA(x0, 0.f);
    publish(qv, qP0, 1u);
  }

  for (int t = 0; t < TT; ++t) {
    float xnext = 0.f;                     // prefetch x(t+1), plain cached load
    if (c < 16 && t < TT - 1)
      xnext = X[(size_t)(base + w) * (TT * DD) + (t + 1) * DD + c];

    // ---- wait for all 128 blocks to have published q_t ----
    uint32_t target = (uint32_t)(t + 1);
    for (;;) {
      uint32_t f0 = __hip_atomic_load(&flags[c],      __ATOMIC_RELAXED, __HIP_MEMORY_SCOPE_AGENT);
      uint32_t f1 = __hip_atomic_load(&flags[64 + c], __ATOMIC_RELAXED, __HIP_MEMORY_SCOPE_AGENT);
      if (__all((f0 >= target) && (f1 >= target))) break;
      __builtin_amdgcn_s_sleep(4);
    }
    asm volatile("" ::: "memory");

    // ---- phase B: Aq = A @ q_t (MFMA); B-frags via sc1 u64 loads ----
    uint32_t* qP = (t & 1) ? qP1 : qP0;
    uint32_t* qrow = qP + (size_t)(nt * 16 + m) * (NN / 2) + kh * 256 + quad * 4;
    f32x4 acc = {0.f, 0.f, 0.f, 0.f};
    #pragma unroll 4
    for (int ch = 0; ch < 16; ++ch) {
      bf16x8 av = *(const bf16x8*)(afp + ch * 512);
      unsigned long long u01 = __hip_atomic_load(
          (unsigned long long*)(qrow + ch * 16), __ATOMIC_RELAXED, __HIP_MEMORY_SCOPE_AGENT);
      unsigned long long u23 = __hip_atomic_load(
          (unsigned long long*)(qrow + ch * 16 + 2), __ATOMIC_RELAXED, __HIP_MEMORY_SCOPE_AGENT);
      union { unsigned long long q[2]; bf16x8 v; } bb;
      bb.q[0] = u01; bb.q[1] = u23;
      acc = __builtin_amdgcn_mfma_f32_16x16x32_bf16(av, bb.v, acc, 0, 0, 0);
    }
    sh_part[w * 64 + c] = acc;
    __syncthreads();

    // D layout: col=lane&15, row=(lane>>4)*4+reg. Thread (row=w, col=c): sum 4 K-quarters.
    const float* pf = (const float*)sh_part;
    float aqv = 0.f;
    #pragma unroll
    for (int kh2 = 0; kh2 < 4; ++kh2)
      aqv += pf[((kh2 * 4 + (c >> 4)) * 64 + (w >> 2) * 16 + (c & 15)) * 4 + (w & 3)];

    // ---- update (gates/c/h in registers) + fused output projection ----
    creg = gf * (creg + aqv) + gi * gg;
    hreg = go * tanh_(creg);
    float red = hreg * wdc;
    #pragma unroll
    for (int off = 32; off; off >>= 1) red += __shfl_xor(red, off);
    if (c == 0) Out[(size_t)(base + w) * TT + t] = red + bdc;

    // ---- phase A(t+1) + publish q_{t+1} ----
    if (t < TT - 1) {
      float qv = phaseA(xnext, hreg);
      publish(qv, (t & 1) ? qP0 : qP1, (uint32_t)(t + 2));
    }
  }
}

extern "C" void kernel_launch(void* const* d_in, const int* in_sizes, int n_in,
                              void* d_out, int out_size, void* d_ws, size_t ws_size,
                              hipStream_t stream) {
  const float* X    = (const float*)d_in[0];
  const float* Af   = (const float*)d_in[1];
  const float* Wih  = (const float*)d_in[2];
  const float* Whh  = (const float*)d_in[3];
  const float* Bias = (const float*)d_in[4];
  const float* Wq   = (const float*)d_in[5];
  const float* Bq   = (const float*)d_in[6];
  const float* Wd   = (const float*)d_in[7];
  const float* Bd   = (const float*)d_in[8];
  float* Out = (float*)d_out;

  char* ws = (char*)d_ws;
  uint32_t* flags = (uint32_t*)ws;                         // 128 u32 @0
  uint32_t* qP0   = (uint32_t*)(ws + 1024);                // 64*1024 u32 = 256 KB
  uint32_t* qP1   = (uint32_t*)(ws + 1024 + 262144);       // 256 KB

  hipFuncSetAttribute((const void*)rgcn_persist,
                      hipFuncAttributeMaxDynamicSharedMemorySize, SMEM_BYTES);
  hipMemsetAsync(ws, 0, 1024, stream);                     // zero flags (poisoned 0xAA!)
  hipLaunchKernelGGL(rgcn_persist, dim3(NBLK), dim3(NTHR), SMEM_BYTES, stream,
                     X, Af, Wih, Whh, Bias, Wq, Bq, Wd, Bd, Out, qP0, qP1, flags);
}

// Round 10
// 9170.914 us; speedup vs baseline: 1.9339x; 1.0583x over previous
//
#include <hip/hip_runtime.h>
#include <stdint.h>

#define NN 2048
#define TT 365
#define DD 16
#define HH 64
#define NBLK 128      // 16 rows per block, all co-resident
#define NTHR 1024     // 16 waves
#define SMEM_BYTES 133120

typedef __attribute__((ext_vector_type(8))) short bf16x8;
typedef __attribute__((ext_vector_type(4))) float f32x4;

__device__ __forceinline__ unsigned short f2bf(float f) {
  union { float f; uint32_t u; } z; z.f = f;
  uint32_t r = z.u + 0x7fffu + ((z.u >> 16) & 1u);
  return (unsigned short)(r >> 16);
}
__device__ __forceinline__ float lo16(uint32_t u) {
  union { uint32_t u; float f; } z; z.u = u << 16; return z.f;
}
__device__ __forceinline__ float hi16(uint32_t u) {
  union { uint32_t u; float f; } z; z.u = u & 0xffff0000u; return z.f;
}
__device__ __forceinline__ float sigmoid_(float x) { return 1.f / (1.f + __expf(-x)); }
__device__ __forceinline__ float tanh_(float x) {
  float ax = fabsf(x);
  float e = __expf(-2.f * ax);
  float r = (1.f - e) / (1.f + e);
  return x < 0.f ? -r : r;
}

// Persistent, fence-free (device-coherent relaxed atomics only). R9 +:
//   (1) phase-B q loads fully prefetched (one latency exposure, not 4)
//   (2) coalesced publish (8 lanes -> 32 contiguous bytes)
//   (3) single-wave flag polling
__global__ __launch_bounds__(NTHR) void rgcn_persist(
    const float* __restrict__ X, const float* __restrict__ Af,
    const float* __restrict__ Wih, const float* __restrict__ Whh,
    const float* __restrict__ Bias, const float* __restrict__ Wq,
    const float* __restrict__ Bq, const float* __restrict__ Wd,
    const float* __restrict__ Bd, float* __restrict__ Out,
    uint32_t* qP0, uint32_t* qP1, uint32_t* flags)
{
  extern __shared__ __align__(16) char smem[];
  uint2*          whh2    = (uint2*)smem;                      // [64][64] bf16x4   32768
  uint2*          wih2    = (uint2*)(smem + 32768);            // [16][64] bf16x4    8192
  uint32_t*       wqp     = (uint32_t*)(smem + 40960);         // [32][64] bf16x2    8192
  unsigned short* afrag   = (unsigned short*)(smem + 49152);   // [64 kc][64 ln][8]  65536
  f32x4*          sh_part = (f32x4*)(smem + 114688);           // [16][64] f32x4     16384
  unsigned short* sh_q    = (unsigned short*)(smem + 131072);  // [16][64] bf16       2048

  const int tid = threadIdx.x;
  const int w = tid >> 6;        // wave 0..15
  const int c = tid & 63;        // lane
  const int base = blockIdx.x * 16;

  // ---- one-time: pack weights bf16 into LDS ----
  for (int idx = tid; idx < 64 * 64; idx += NTHR) {
    int k = idx >> 6, cc = idx & 63;
    uint2 p;
    p.x = (uint32_t)f2bf(Whh[k * 256 + cc])       | ((uint32_t)f2bf(Whh[k * 256 + 64 + cc]) << 16);
    p.y = (uint32_t)f2bf(Whh[k * 256 + 128 + cc]) | ((uint32_t)f2bf(Whh[k * 256 + 192 + cc]) << 16);
    whh2[idx] = p;
  }
  for (int idx = tid; idx < 16 * 64; idx += NTHR) {
    int k = idx >> 6, cc = idx & 63;
    uint2 p;
    p.x = (uint32_t)f2bf(Wih[k * 256 + cc])       | ((uint32_t)f2bf(Wih[k * 256 + 64 + cc]) << 16);
    p.y = (uint32_t)f2bf(Wih[k * 256 + 128 + cc]) | ((uint32_t)f2bf(Wih[k * 256 + 192 + cc]) << 16);
    wih2[idx] = p;
  }
  for (int idx = tid; idx < 32 * 64; idx += NTHR) {
    int kk = idx >> 6, cc = idx & 63;
    wqp[idx] = (uint32_t)f2bf(Wq[(2 * kk) * 64 + cc]) |
               ((uint32_t)f2bf(Wq[(2 * kk + 1) * 64 + cc]) << 16);
  }
  // ---- one-time: own 16 A-rows -> bf16 MFMA A-fragment layout ----
  for (int i = tid; i < 16 * NN; i += NTHR) {
    int r = i >> 11, k = i & (NN - 1);
    unsigned short v = f2bf(Af[(size_t)(base + r) * NN + k]);
    afrag[(k >> 5) * 512 + (((k >> 3) & 3) * 16 + r) * 8 + (k & 7)] = v;
  }
  __syncthreads();

  const float b_i = Bias[c], b_f = Bias[64 + c], b_g = Bias[128 + c], b_o = Bias[192 + c];
  const float bqc = Bq[c], wdc = Wd[c], bdc = Bd[0];
  const int m = c & 15, quad = c >> 4;
  const int nt = w & 3, kh = w >> 2;           // phase B: 16-col tile, 512-K quarter
  const unsigned short* afp = afrag + (kh * 16) * 512 + c * 8;

  float creg = 0.f, hreg = 0.f;
  float gi, gf, gg, go;

  auto phaseA = [&](float xreg, float hv) -> float {
    float ai = b_i, af_ = b_f, ag = b_g, ao = b_o, aq = bqc;
    #pragma unroll
    for (int k = 0; k < 16; ++k) {
      float xv = __shfl(xreg, k, 64);
      uint2 p = wih2[k * 64 + c];
      ai += xv * lo16(p.x); af_ += xv * hi16(p.x);
      ag += xv * lo16(p.y); ao += xv * hi16(p.y);
    }
    #pragma unroll 8
    for (int kk = 0; kk < 32; ++kk) {
      float h0 = __shfl(hv, 2 * kk, 64);
      float h1 = __shfl(hv, 2 * kk + 1, 64);
      uint2 p0 = whh2[(2 * kk) * 64 + c];
      uint2 p1 = whh2[(2 * kk + 1) * 64 + c];
      uint32_t uq = wqp[kk * 64 + c];
      ai  += h0 * lo16(p0.x) + h1 * lo16(p1.x);
      af_ += h0 * hi16(p0.x) + h1 * hi16(p1.x);
      ag  += h0 * lo16(p0.y) + h1 * lo16(p1.y);
      ao  += h0 * hi16(p0.y) + h1 * hi16(p1.y);
      aq  += h0 * lo16(uq)  + h1 * hi16(uq);
    }
    gi = sigmoid_(ai); gf = sigmoid_(af_); gg = tanh_(ag); go = sigmoid_(ao);
    return tanh_(aq);
  };

  auto publish = [&](float qv, uint32_t* qP, uint32_t flagval) {
    sh_q[w * 64 + c] = f2bf(qv);
    __syncthreads();
    if (tid < 512) {                       // coalesced: 8 lanes -> 32 contiguous bytes
      int col = tid >> 3, pr = tid & 7;
      uint32_t v = (uint32_t)sh_q[(2 * pr) * 64 + col] |
                   ((uint32_t)sh_q[(2 * pr + 1) * 64 + col] << 16);
      __hip_atomic_store(&qP[(size_t)col * (NN / 2) + (base >> 1) + pr], v,
                         __ATOMIC_RELAXED, __HIP_MEMORY_SCOPE_AGENT);
    }
    __builtin_amdgcn_s_waitcnt(0);         // own sc1 stores acked at coherence point
    asm volatile("" ::: "memory");
    __syncthreads();                       // all storing waves drained
    if (tid == 0)
      __hip_atomic_store(&flags[blockIdx.x], flagval,
                         __ATOMIC_RELAXED, __HIP_MEMORY_SCOPE_AGENT);
  };

  // bootstrap: phase A(0) with h = 0, publish q_0 (flag=1)
  {
    float x0 = (c < 16) ? X[(size_t)(base + w) * (TT * DD) + c] : 0.f;
    float qv = phaseA(x0, 0.f);
    publish(qv, qP0, 1u);
  }

  for (int t = 0; t < TT; ++t) {
    float xnext = 0.f;                     // prefetch x(t+1)
    if (c < 16 && t < TT - 1)
      xnext = X[(size_t)(base + w) * (TT * DD) + (t + 1) * DD + c];

    // ---- wait for all 128 blocks (wave 0 polls, others park at barrier) ----
    uint32_t target = (uint32_t)(t + 1);
    if (w == 0) {
      for (;;) {
        uint32_t f0 = __hip_atomic_load(&flags[c],      __ATOMIC_RELAXED, __HIP_MEMORY_SCOPE_AGENT);
        uint32_t f1 = __hip_atomic_load(&flags[64 + c], __ATOMIC_RELAXED, __HIP_MEMORY_SCOPE_AGENT);
        if (__all((f0 >= target) && (f1 >= target))) break;
        __builtin_amdgcn_s_sleep(1);
      }
    }
    __syncthreads();
    asm volatile("" ::: "memory");

    // ---- phase B: prefetch ALL q (32 u64 coherent loads in flight), then MFMA ----
    uint32_t* qP = (t & 1) ? qP1 : qP0;
    uint32_t* qrow = qP + (size_t)(nt * 16 + m) * (NN / 2) + kh * 256 + quad * 4;
    unsigned long long qv[32];
    #pragma unroll
    for (int ch = 0; ch < 16; ++ch) {
      qv[2 * ch]     = __hip_atomic_load((unsigned long long*)(qrow + ch * 16),
                                         __ATOMIC_RELAXED, __HIP_MEMORY_SCOPE_AGENT);
      qv[2 * ch + 1] = __hip_atomic_load((unsigned long long*)(qrow + ch * 16 + 2),
                                         __ATOMIC_RELAXED, __HIP_MEMORY_SCOPE_AGENT);
    }
    f32x4 acc = {0.f, 0.f, 0.f, 0.f};
    #pragma unroll
    for (int ch = 0; ch < 16; ++ch) {
      bf16x8 av = *(const bf16x8*)(afp + ch * 512);
      union { unsigned long long q[2]; bf16x8 v; } bb;
      bb.q[0] = qv[2 * ch]; bb.q[1] = qv[2 * ch + 1];
      acc = __builtin_amdgcn_mfma_f32_16x16x32_bf16(av, bb.v, acc, 0, 0, 0);
    }
    sh_part[w * 64 + c] = acc;
    __syncthreads();

    // D layout: col=lane&15, row=(lane>>4)*4+reg. Thread (row=w, col=c): sum 4 K-quarters.
    const float* pf = (const float*)sh_part;
    float aqv = 0.f;
    #pragma unroll
    for (int kh2 = 0; kh2 < 4; ++kh2)
      aqv += pf[((kh2 * 4 + (c >> 4)) * 64 + (w >> 2) * 16 + (c & 15)) * 4 + (w & 3)];

    // ---- update + fused output projection ----
    creg = gf * (creg + aqv) + gi * gg;
    hreg = go * tanh_(creg);
    float red = hreg * wdc;
    #pragma unroll
    for (int off = 32; off; off >>= 1) red += __shfl_xor(red, off);
    if (c == 0) Out[(size_t)(base + w) * TT + t] = red + bdc;

    // ---- phase A(t+1) + publish q_{t+1} ----
    if (t < TT - 1) {
      float qv2 = phaseA(xnext, hreg);
      publish(qv2, (t & 1) ? qP0 : qP1, (uint32_t)(t + 2));
    }
  }
}

extern "C" void kernel_launch(void* const* d_in, const int* in_sizes, int n_in,
                              void* d_out, int out_size, void* d_ws, size_t ws_size,
                              hipStream_t stream) {
  const float* X    = (const float*)d_in[0];
  const float* Af   = (const float*)d_in[1];
  const float* Wih  = (const float*)d_in[2];
  const float* Whh  = (const float*)d_in[3];
  const float* Bias = (const float*)d_in[4];
  const float* Wq   = (const float*)d_in[5];
  const float* Bq   = (const float*)d_in[6];
  const float* Wd   = (const float*)d_in[7];
  const float* Bd   = (const float*)d_in[8];
  float* Out = (float*)d_out;

  char* ws = (char*)d_ws;
  uint32_t* flags = (uint32_t*)ws;                         // 128 u32 @0
  uint32_t* qP0   = (uint32_t*)(ws + 1024);                // 64*1024 u32 = 256 KB
  uint32_t* qP1   = (uint32_t*)(ws + 1024 + 262144);       // 256 KB

  hipFuncSetAttribute((const void*)rgcn_persist,
                      hipFuncAttributeMaxDynamicSharedMemorySize, SMEM_BYTES);
  hipMemsetAsync(ws, 0, 1024, stream);                     // zero flags (poisoned 0xAA!)
  hipLaunchKernelGGL(rgcn_persist, dim3(NBLK), dim3(NTHR), SMEM_BYTES, stream,
                     X, Af, Wih, Whh, Bias, Wq, Bq, Wd, Bd, Out, qP0, qP1, flags);
}

// Round 11
// 8295.937 us; speedup vs baseline: 2.1379x; 1.1055x over previous
//
#include <hip/hip_runtime.h>
#include <stdint.h>

#define NN 2048
#define TT 365
#define DD 16
#define HH 64
#define NBLK 128      // 16 rows per block, all co-resident (1 block/CU, LDS-bound)
#define NTHR 1024     // 16 waves
#define SMEM_BYTES 133120

typedef __attribute__((ext_vector_type(8))) short bf16x8;
typedef __attribute__((ext_vector_type(4))) float f32x4;

__device__ __forceinline__ unsigned short f2bf(float f) {
  union { float f; uint32_t u; } z; z.f = f;
  uint32_t r = z.u + 0x7fffu + ((z.u >> 16) & 1u);
  return (unsigned short)(r >> 16);
}
__device__ __forceinline__ float lo16(uint32_t u) {
  union { uint32_t u; float f; } z; z.u = u << 16; return z.f;
}
__device__ __forceinline__ float hi16(uint32_t u) {
  union { uint32_t u; float f; } z; z.u = u & 0xffff0000u; return z.f;
}
__device__ __forceinline__ float sigmoid_(float x) { return 1.f / (1.f + __expf(-x)); }
__device__ __forceinline__ float tanh_(float x) {
  float ax = fabsf(x);
  float e = __expf(-2.f * ax);
  float r = (1.f - e) / (1.f + e);
  return x < 0.f ? -r : r;
}

// Persistent, fence-free. R10 + latency OVERLAP:
//  - publish-early: q_{t+1} computed+published right after update; the expensive
//    4-gate matvec for step t runs at the START of iteration t (hides other
//    blocks' publish/ack/visibility latency under local compute)
//  - demand-driven phase B: wave kh polls only its 32 source blocks with ONE
//    batched sc1 flag load + ballot; processes ready 32-k chunks out of order
__global__ __launch_bounds__(NTHR) void rgcn_persist(
    const float* __restrict__ X, const float* __restrict__ Af,
    const float* __restrict__ Wih, const float* __restrict__ Whh,
    const float* __restrict__ Bias, const float* __restrict__ Wq,
    const float* __restrict__ Bq, const float* __restrict__ Wd,
    const float* __restrict__ Bd, float* __restrict__ Out,
    uint32_t* qP0, uint32_t* qP1, uint32_t* flags)
{
  extern __shared__ __align__(16) char smem[];
  uint2*          whh2    = (uint2*)smem;                      // [64][64] bf16x4   32768
  uint2*          wih2    = (uint2*)(smem + 32768);            // [16][64] bf16x4    8192
  uint32_t*       wqp     = (uint32_t*)(smem + 40960);         // [32][64] bf16x2    8192
  unsigned short* afrag   = (unsigned short*)(smem + 49152);   // [64 kc][64 ln][8]  65536
  f32x4*          sh_part = (f32x4*)(smem + 114688);           // [16][64] f32x4     16384
  unsigned short* sh_q    = (unsigned short*)(smem + 131072);  // [16][64] bf16       2048

  const int tid = threadIdx.x;
  const int w = tid >> 6;        // wave 0..15
  const int c = tid & 63;        // lane
  const int base = blockIdx.x * 16;

  // ---- one-time: pack weights bf16 into LDS ----
  for (int idx = tid; idx < 64 * 64; idx += NTHR) {
    int k = idx >> 6, cc = idx & 63;
    uint2 p;
    p.x = (uint32_t)f2bf(Whh[k * 256 + cc])       | ((uint32_t)f2bf(Whh[k * 256 + 64 + cc]) << 16);
    p.y = (uint32_t)f2bf(Whh[k * 256 + 128 + cc]) | ((uint32_t)f2bf(Whh[k * 256 + 192 + cc]) << 16);
    whh2[idx] = p;
  }
  for (int idx = tid; idx < 16 * 64; idx += NTHR) {
    int k = idx >> 6, cc = idx & 63;
    uint2 p;
    p.x = (uint32_t)f2bf(Wih[k * 256 + cc])       | ((uint32_t)f2bf(Wih[k * 256 + 64 + cc]) << 16);
    p.y = (uint32_t)f2bf(Wih[k * 256 + 128 + cc]) | ((uint32_t)f2bf(Wih[k * 256 + 192 + cc]) << 16);
    wih2[idx] = p;
  }
  for (int idx = tid; idx < 32 * 64; idx += NTHR) {
    int kk = idx >> 6, cc = idx & 63;
    wqp[idx] = (uint32_t)f2bf(Wq[(2 * kk) * 64 + cc]) |
               ((uint32_t)f2bf(Wq[(2 * kk + 1) * 64 + cc]) << 16);
  }
  // ---- one-time: own 16 A-rows -> bf16 MFMA A-fragment layout ----
  for (int i = tid; i < 16 * NN; i += NTHR) {
    int r = i >> 11, k = i & (NN - 1);
    unsigned short v = f2bf(Af[(size_t)(base + r) * NN + k]);
    afrag[(k >> 5) * 512 + (((k >> 3) & 3) * 16 + r) * 8 + (k & 7)] = v;
  }
  __syncthreads();

  const float b_i = Bias[c], b_f = Bias[64 + c], b_g = Bias[128 + c], b_o = Bias[192 + c];
  const float bqc = Bq[c], wdc = Wd[c], bdc = Bd[0];
  const int m = c & 15, quad = c >> 4;
  const int nt = w & 3, kh = w >> 2;           // phase B: 16-col tile, 512-K quarter
  const unsigned short* afp = afrag + (kh * 16) * 512 + c * 8;
  const int sbbase = kh * 32;                  // this wave's 32 source blocks

  float creg = 0.f, hreg = 0.f;

  auto publish = [&](float qv, uint32_t* qP, uint32_t flagval) {
    sh_q[w * 64 + c] = f2bf(qv);
    __syncthreads();
    if (tid < 512) {                       // coalesced: 8 lanes -> 32 contiguous bytes
      int col = tid >> 3, pr = tid & 7;
      uint32_t v = (uint32_t)sh_q[(2 * pr) * 64 + col] |
                   ((uint32_t)sh_q[(2 * pr + 1) * 64 + col] << 16);
      __hip_atomic_store(&qP[(size_t)col * (NN / 2) + (base >> 1) + pr], v,
                         __ATOMIC_RELAXED, __HIP_MEMORY_SCOPE_AGENT);
    }
    __builtin_amdgcn_s_waitcnt(0);         // own sc1 stores acked at coherence point
    asm volatile("" ::: "memory");
    __syncthreads();                       // all storing waves drained
    if (tid == 0)
      __hip_atomic_store(&flags[blockIdx.x], flagval,
                         __ATOMIC_RELAXED, __HIP_MEMORY_SCOPE_AGENT);
  };

  // bootstrap: q_0 = tanh(b_q) (h=0) -- no compute, publish immediately
  publish(tanh_(bqc), qP0, 1u);

  float xcur = (c < 16) ? X[(size_t)(base + w) * (TT * DD) + c] : 0.f;

  for (int t = 0; t < TT; ++t) {
    // ---- gates_t from x_t, h_{t-1} (expensive part; overlaps others' publish) ----
    float ai = b_i, af_ = b_f, ag = b_g, ao = b_o;
    #pragma unroll
    for (int k = 0; k < 16; ++k) {
      float xv = __shfl(xcur, k, 64);
      uint2 p = wih2[k * 64 + c];
      ai += xv * lo16(p.x); af_ += xv * hi16(p.x);
      ag += xv * lo16(p.y); ao += xv * hi16(p.y);
    }
    #pragma unroll 8
    for (int kk = 0; kk < 32; ++kk) {
      float h0 = __shfl(hreg, 2 * kk, 64);
      float h1 = __shfl(hreg, 2 * kk + 1, 64);
      uint2 p0 = whh2[(2 * kk) * 64 + c];
      uint2 p1 = whh2[(2 * kk + 1) * 64 + c];
      ai  += h0 * lo16(p0.x) + h1 * lo16(p1.x);
      af_ += h0 * hi16(p0.x) + h1 * hi16(p1.x);
      ag  += h0 * lo16(p0.y) + h1 * lo16(p1.y);
      ao  += h0 * hi16(p0.y) + h1 * hi16(p1.y);
    }
    float gi = sigmoid_(ai), gf = sigmoid_(af_), gg = tanh_(ag), go = sigmoid_(ao);

    // prefetch x_{t+1} (plain cached load, consumed next iteration)
    float xnext = 0.f;
    if (c < 16 && t < TT - 1)
      xnext = X[(size_t)(base + w) * (TT * DD) + (t + 1) * DD + c];

    // ---- phase B: demand-driven Aq_t. Wave kh consumes sources sbbase..+31 ----
    uint32_t* qP = (t & 1) ? qP1 : qP0;
    uint32_t* qrow = qP + (size_t)(nt * 16 + m) * (NN / 2) + kh * 256 + quad * 4;
    const uint32_t target = (uint32_t)(t + 1);
    f32x4 acc = {0.f, 0.f, 0.f, 0.f};
    uint32_t done = 0;
    for (;;) {
      // one batched flag load: lane c sees flags[sbbase + (c&31)]
      uint32_t fv = __hip_atomic_load(&flags[sbbase + (c & 31)],
                                      __ATOMIC_RELAXED, __HIP_MEMORY_SCOPE_AGENT);
      uint32_t m32 = (uint32_t)__ballot(fv >= target);   // bits 0..31 valid
      uint32_t pairs = m32 & (m32 >> 1) & 0x55555555u;   // bit 2ch: chunk ch ready
      #pragma unroll
      for (int ch = 0; ch < 16; ++ch) {
        if (!(done & (1u << ch)) && ((pairs >> (2 * ch)) & 1u)) {
          unsigned long long u01 = __hip_atomic_load(
              (unsigned long long*)(qrow + ch * 16), __ATOMIC_RELAXED, __HIP_MEMORY_SCOPE_AGENT);
          unsigned long long u23 = __hip_atomic_load(
              (unsigned long long*)(qrow + ch * 16 + 2), __ATOMIC_RELAXED, __HIP_MEMORY_SCOPE_AGENT);
          bf16x8 av = *(const bf16x8*)(afp + ch * 512);
          union { unsigned long long q[2]; bf16x8 v; } bb;
          bb.q[0] = u01; bb.q[1] = u23;
          acc = __builtin_amdgcn_mfma_f32_16x16x32_bf16(av, bb.v, acc, 0, 0, 0);
          done |= (1u << ch);
        }
      }
      if (done == 0xFFFFu) break;
      __builtin_amdgcn_s_sleep(1);
    }
    sh_part[w * 64 + c] = acc;
    __syncthreads();

    // D layout: col=lane&15, row=(lane>>4)*4+reg. Thread (row=w, col=c): sum 4 K-quarters.
    const float* pf = (const float*)sh_part;
    float aqv = 0.f;
    #pragma unroll
    for (int kh2 = 0; kh2 < 4; ++kh2)
      aqv += pf[((kh2 * 4 + (c >> 4)) * 64 + (w >> 2) * 16 + (c & 15)) * 4 + (w & 3)];

    // ---- update + fused output projection ----
    creg = gf * (creg + aqv) + gi * gg;
    hreg = go * tanh_(creg);
    float red = hreg * wdc;
    #pragma unroll
    for (int off = 32; off; off >>= 1) red += __shfl_xor(red, off);
    if (c == 0) Out[(size_t)(base + w) * TT + t] = red + bdc;

    // ---- publish-early: q_{t+1} (small matvec) -> flag t+2 ----
    if (t < TT - 1) {
      float aq = bqc;
      #pragma unroll 8
      for (int kk = 0; kk < 32; ++kk) {
        float h0 = __shfl(hreg, 2 * kk, 64);
        float h1 = __shfl(hreg, 2 * kk + 1, 64);
        uint32_t uq = wqp[kk * 64 + c];
        aq += h0 * lo16(uq) + h1 * hi16(uq);
      }
      publish(tanh_(aq), (t & 1) ? qP0 : qP1, (uint32_t)(t + 2));
    }
    xcur = xnext;
  }
}

extern "C" void kernel_launch(void* const* d_in, const int* in_sizes, int n_in,
                              void* d_out, int out_size, void* d_ws, size_t ws_size,
                              hipStream_t stream) {
  const float* X    = (const float*)d_in[0];
  const float* Af   = (const float*)d_in[1];
  const float* Wih  = (const float*)d_in[2];
  const float* Whh  = (const float*)d_in[3];
  const float* Bias = (const float*)d_in[4];
  const float* Wq   = (const float*)d_in[5];
  const float* Bq   = (const float*)d_in[6];
  const float* Wd   = (const float*)d_in[7];
  const float* Bd   = (const float*)d_in[8];
  float* Out = (float*)d_out;

  char* ws = (char*)d_ws;
  uint32_t* flags = (uint32_t*)ws;                         // 128 u32 @0
  uint32_t* qP0   = (uint32_t*)(ws + 1024);                // 64*1024 u32 = 256 KB
  uint32_t* qP1   = (uint32_t*)(ws + 1024 + 262144);       // 256 KB

  hipFuncSetAttribute((const void*)rgcn_persist,
                      hipFuncAttributeMaxDynamicSharedMemorySize, SMEM_BYTES);
  hipMemsetAsync(ws, 0, 1024, stream);                     // zero flags (poisoned 0xAA!)
  hipLaunchKernelGGL(rgcn_persist, dim3(NBLK), dim3(NTHR), SMEM_BYTES, stream,
                     X, Af, Wih, Whh, Bias, Wq, Bq, Wd, Bd, Out, qP0, qP1, flags);
}

// Round 12
// 6489.330 us; speedup vs baseline: 2.7331x; 1.2784x over previous
//
#include <hip/hip_runtime.h>
#include <stdint.h>

#define NN 2048
#define TT 365
#define DD 16
#define HH 64
#define NBLK 128      // 16 rows per block, all co-resident (1 block/CU, LDS-bound)
#define NTHR 1024     // 16 waves
#define SMEM_BYTES 133120

typedef __attribute__((ext_vector_type(8))) short bf16x8;
typedef __attribute__((ext_vector_type(4))) float f32x4;

__device__ __forceinline__ unsigned short f2bf(float f) {
  union { float f; uint32_t u; } z; z.f = f;
  uint32_t r = z.u + 0x7fffu + ((z.u >> 16) & 1u);
  return (unsigned short)(r >> 16);
}
__device__ __forceinline__ float lo16(uint32_t u) {
  union { uint32_t u; float f; } z; z.u = u << 16; return z.f;
}
__device__ __forceinline__ float hi16(uint32_t u) {
  union { uint32_t u; float f; } z; z.u = u & 0xffff0000u; return z.f;
}
__device__ __forceinline__ float sigmoid_(float x) { return 1.f / (1.f + __expf(-x)); }
__device__ __forceinline__ float tanh_(float x) {
  float ax = fabsf(x);
  float e = __expf(-2.f * ax);
  float r = (1.f - e) / (1.f + e);
  return x < 0.f ? -r : r;
}

// R12: q exchange via L3 with LINE-GRANULE CACHED reads.
//  - publish: sc1 write-through stores (q data always fresh in L3; L2 never dirty for q)
//  - consume: wave0 polls flags (sc1) -> fence(acquire,agent) = s_waitcnt+buffer_inv
//    (flash-inv L1 + clean L2 lines) -> __syncthreads -> PLAIN 16B q loads
//    (2048 line fetches/block instead of 32K 8B coherent transactions; same-XCD
//    blocks share L2 lines). No release fences anywhere (no wbl2 tag-walks).
//  - Out stores sc1 write-through so no needed dirty line exists at inv time.
__global__ __launch_bounds__(NTHR) void rgcn_persist(
    const float* __restrict__ X, const float* __restrict__ Af,
    const float* __restrict__ Wih, const float* __restrict__ Whh,
    const float* __restrict__ Bias, const float* __restrict__ Wq,
    const float* __restrict__ Bq, const float* __restrict__ Wd,
    const float* __restrict__ Bd, float* __restrict__ Out,
    uint32_t* qP0, uint32_t* qP1, uint32_t* flags)
{
  extern __shared__ __align__(16) char smem[];
  uint2*          whh2    = (uint2*)smem;                      // [64][64] bf16x4   32768
  uint2*          wih2    = (uint2*)(smem + 32768);            // [16][64] bf16x4    8192
  uint32_t*       wqp     = (uint32_t*)(smem + 40960);         // [32][64] bf16x2    8192
  unsigned short* afrag   = (unsigned short*)(smem + 49152);   // [64 kc][64 ln][8]  65536
  f32x4*          sh_part = (f32x4*)(smem + 114688);           // [16][64] f32x4     16384
  unsigned short* sh_q    = (unsigned short*)(smem + 131072);  // [16][64] bf16       2048

  const int tid = threadIdx.x;
  const int w = tid >> 6;        // wave 0..15
  const int c = tid & 63;        // lane
  const int base = blockIdx.x * 16;

  // ---- one-time: pack weights bf16 into LDS ----
  for (int idx = tid; idx < 64 * 64; idx += NTHR) {
    int k = idx >> 6, cc = idx & 63;
    uint2 p;
    p.x = (uint32_t)f2bf(Whh[k * 256 + cc])       | ((uint32_t)f2bf(Whh[k * 256 + 64 + cc]) << 16);
    p.y = (uint32_t)f2bf(Whh[k * 256 + 128 + cc]) | ((uint32_t)f2bf(Whh[k * 256 + 192 + cc]) << 16);
    whh2[idx] = p;
  }
  for (int idx = tid; idx < 16 * 64; idx += NTHR) {
    int k = idx >> 6, cc = idx & 63;
    uint2 p;
    p.x = (uint32_t)f2bf(Wih[k * 256 + cc])       | ((uint32_t)f2bf(Wih[k * 256 + 64 + cc]) << 16);
    p.y = (uint32_t)f2bf(Wih[k * 256 + 128 + cc]) | ((uint32_t)f2bf(Wih[k * 256 + 192 + cc]) << 16);
    wih2[idx] = p;
  }
  for (int idx = tid; idx < 32 * 64; idx += NTHR) {
    int kk = idx >> 6, cc = idx & 63;
    wqp[idx] = (uint32_t)f2bf(Wq[(2 * kk) * 64 + cc]) |
               ((uint32_t)f2bf(Wq[(2 * kk + 1) * 64 + cc]) << 16);
  }
  // ---- one-time: own 16 A-rows -> bf16 MFMA A-fragment layout ----
  for (int i = tid; i < 16 * NN; i += NTHR) {
    int r = i >> 11, k = i & (NN - 1);
    unsigned short v = f2bf(Af[(size_t)(base + r) * NN + k]);
    afrag[(k >> 5) * 512 + (((k >> 3) & 3) * 16 + r) * 8 + (k & 7)] = v;
  }
  __syncthreads();

  const float b_i = Bias[c], b_f = Bias[64 + c], b_g = Bias[128 + c], b_o = Bias[192 + c];
  const float bqc = Bq[c], wdc = Wd[c], bdc = Bd[0];
  const int m = c & 15, quad = c >> 4;
  const int nt = w & 3, kh = w >> 2;           // phase B: 16-col tile, 512-node quarter
  const unsigned short* afp = afrag + (kh * 16) * 512 + c * 8;

  float creg = 0.f, hreg = 0.f;

  auto publish = [&](float qv, uint32_t* qP, uint32_t flagval) {
    sh_q[w * 64 + c] = f2bf(qv);
    __syncthreads();
    if (tid < 256) {                       // 4 u64 per col; 4 lanes -> 32 contiguous B
      int col = tid >> 2, pr = tid & 3;
      uint32_t lo = (uint32_t)sh_q[(4 * pr + 0) * 64 + col] |
                    ((uint32_t)sh_q[(4 * pr + 1) * 64 + col] << 16);
      uint32_t hi = (uint32_t)sh_q[(4 * pr + 2) * 64 + col] |
                    ((uint32_t)sh_q[(4 * pr + 3) * 64 + col] << 16);
      unsigned long long v = (unsigned long long)lo | ((unsigned long long)hi << 32);
      __hip_atomic_store((unsigned long long*)(qP + (size_t)col * (NN / 2) + (base >> 1) + 2 * pr),
                         v, __ATOMIC_RELAXED, __HIP_MEMORY_SCOPE_AGENT);
    }
    __builtin_amdgcn_s_waitcnt(0);         // own sc1 stores acked at coherence point
    asm volatile("" ::: "memory");
    __syncthreads();                       // all storing waves drained
    if (tid == 0)
      __hip_atomic_store(&flags[blockIdx.x], flagval,
                         __ATOMIC_RELAXED, __HIP_MEMORY_SCOPE_AGENT);
  };

  // bootstrap: q_0 = tanh(b_q) (h=0) -- publish immediately
  publish(tanh_(bqc), qP0, 1u);

  float xcur = (c < 16) ? X[(size_t)(base + w) * (TT * DD) + c] : 0.f;

  for (int t = 0; t < TT; ++t) {
    // ---- gates_t from x_t, h_{t-1} (overlaps other blocks' publish/visibility) ----
    float ai = b_i, af_ = b_f, ag = b_g, ao = b_o;
    #pragma unroll
    for (int k = 0; k < 16; ++k) {
      float xv = __shfl(xcur, k, 64);
      uint2 p = wih2[k * 64 + c];
      ai += xv * lo16(p.x); af_ += xv * hi16(p.x);
      ag += xv * lo16(p.y); ao += xv * hi16(p.y);
    }
    #pragma unroll 8
    for (int kk = 0; kk < 32; ++kk) {
      float h0 = __shfl(hreg, 2 * kk, 64);
      float h1 = __shfl(hreg, 2 * kk + 1, 64);
      uint2 p0 = whh2[(2 * kk) * 64 + c];
      uint2 p1 = whh2[(2 * kk + 1) * 64 + c];
      ai  += h0 * lo16(p0.x) + h1 * lo16(p1.x);
      af_ += h0 * hi16(p0.x) + h1 * hi16(p1.x);
      ag  += h0 * lo16(p0.y) + h1 * lo16(p1.y);
      ao  += h0 * hi16(p0.y) + h1 * hi16(p1.y);
    }
    float gi = sigmoid_(ai), gf = sigmoid_(af_), gg = tanh_(ag), go = sigmoid_(ao);

    // prefetch x_{t+1}
    float xnext = 0.f;
    if (c < 16 && t < TT - 1)
      xnext = X[(size_t)(base + w) * (TT * DD) + (t + 1) * DD + c];

    // ---- wave0: wait q_t from all 128 blocks, then flash-inv L1/L2 (acquire) ----
    if (w == 0) {
      const uint32_t target = (uint32_t)(t + 1);
      for (;;) {
        uint32_t f0 = __hip_atomic_load(&flags[c],      __ATOMIC_RELAXED, __HIP_MEMORY_SCOPE_AGENT);
        uint32_t f1 = __hip_atomic_load(&flags[64 + c], __ATOMIC_RELAXED, __HIP_MEMORY_SCOPE_AGENT);
        if (__all((f0 >= target) && (f1 >= target))) break;
        __builtin_amdgcn_s_sleep(1);
      }
      __builtin_amdgcn_fence(__ATOMIC_ACQUIRE, "agent");   // s_waitcnt + buffer_inv
    }
    __syncthreads();

    // ---- phase B: Aq_t via MFMA; q read with PLAIN CACHED 16B loads ----
    const unsigned short* qbase = (const unsigned short*)((t & 1) ? qP1 : qP0);
    const unsigned short* qrow = qbase + (size_t)(nt * 16 + m) * NN + kh * 512 + quad * 8;
    f32x4 acc = {0.f, 0.f, 0.f, 0.f};
    #pragma unroll
    for (int ch = 0; ch < 16; ++ch) {
      bf16x8 av = *(const bf16x8*)(afp + ch * 512);
      bf16x8 bv = *(const bf16x8*)(qrow + ch * 32);
      acc = __builtin_amdgcn_mfma_f32_16x16x32_bf16(av, bv, acc, 0, 0, 0);
    }
    sh_part[w * 64 + c] = acc;
    __syncthreads();

    // D layout: col=lane&15, row=(lane>>4)*4+reg. Thread (row=w, col=c): sum 4 quarters.
    const float* pf = (const float*)sh_part;
    float aqv = 0.f;
    #pragma unroll
    for (int kh2 = 0; kh2 < 4; ++kh2)
      aqv += pf[((kh2 * 4 + (c >> 4)) * 64 + (w >> 2) * 16 + (c & 15)) * 4 + (w & 3)];

    // ---- update + fused output projection (Out store sc1 write-through) ----
    creg = gf * (creg + aqv) + gi * gg;
    hreg = go * tanh_(creg);
    float red = hreg * wdc;
    #pragma unroll
    for (int off = 32; off; off >>= 1) red += __shfl_xor(red, off);
    if (c == 0) {
      union { float f; uint32_t u; } o; o.f = red + bdc;
      __hip_atomic_store((uint32_t*)&Out[(size_t)(base + w) * TT + t], o.u,
                         __ATOMIC_RELAXED, __HIP_MEMORY_SCOPE_AGENT);
    }

    // ---- publish-early: q_{t+1} (small matvec) -> flag t+2 ----
    if (t < TT - 1) {
      float aq = bqc;
      #pragma unroll 8
      for (int kk = 0; kk < 32; ++kk) {
        float h0 = __shfl(hreg, 2 * kk, 64);
        float h1 = __shfl(hreg, 2 * kk + 1, 64);
        uint32_t uq = wqp[kk * 64 + c];
        aq += h0 * lo16(uq) + h1 * hi16(uq);
      }
      publish(tanh_(aq), (t & 1) ? qP0 : qP1, (uint32_t)(t + 2));
    }
    xcur = xnext;
  }
}

extern "C" void kernel_launch(void* const* d_in, const int* in_sizes, int n_in,
                              void* d_out, int out_size, void* d_ws, size_t ws_size,
                              hipStream_t stream) {
  const float* X    = (const float*)d_in[0];
  const float* Af   = (const float*)d_in[1];
  const float* Wih  = (const float*)d_in[2];
  const float* Whh  = (const float*)d_in[3];
  const float* Bias = (const float*)d_in[4];
  const float* Wq   = (const float*)d_in[5];
  const float* Bq   = (const float*)d_in[6];
  const float* Wd   = (const float*)d_in[7];
  const float* Bd   = (const float*)d_in[8];
  float* Out = (float*)d_out;

  char* ws = (char*)d_ws;
  uint32_t* flags = (uint32_t*)ws;                         // 128 u32 @0
  uint32_t* qP0   = (uint32_t*)(ws + 1024);                // 64*1024 u32 = 256 KB
  uint32_t* qP1   = (uint32_t*)(ws + 1024 + 262144);       // 256 KB

  hipFuncSetAttribute((const void*)rgcn_persist,
                      hipFuncAttributeMaxDynamicSharedMemorySize, SMEM_BYTES);
  hipMemsetAsync(ws, 0, 1024, stream);                     // zero flags (poisoned 0xAA!)
  hipLaunchKernelGGL(rgcn_persist, dim3(NBLK), dim3(NTHR), SMEM_BYTES, stream,
                     X, Af, Wih, Whh, Bias, Wq, Bq, Wd, Bd, Out, qP0, qP1, flags);
}

// Round 13
// 3848.554 us; speedup vs baseline: 4.6084x; 1.6862x over previous
//
#include <hip/hip_runtime.h>
#include <stdint.h>

#define NN 2048
#define TT 365
#define DD 16
#define HH 64
#define NBLK 128      // 16 rows per block, all co-resident (1 block/CU, LDS-bound)
#define NTHR 1024     // 16 waves
#define SMEM_BYTES 150016

typedef __attribute__((ext_vector_type(8))) short bf16x8;
typedef __attribute__((ext_vector_type(4))) float f32x4;

__device__ __forceinline__ unsigned short f2bf(float f) {
  union { float f; uint32_t u; } z; z.f = f;
  uint32_t r = z.u + 0x7fffu + ((z.u >> 16) & 1u);
  return (unsigned short)(r >> 16);
}
__device__ __forceinline__ float sigmoid_(float x) { return 1.f / (1.f + __expf(-x)); }
__device__ __forceinline__ float tanh_(float x) {
  float ax = fabsf(x);
  float e = __expf(-2.f * ax);
  float r = (1.f - e) / (1.f + e);
  return x < 0.f ? -r : r;
}

// R13: phase A via MFMA. gates = [h|x|0](16x96) @ [WhhT;WihT;0](96x256),
// q = h @ WqT — weights staged bf16 in LDS once; each element read once per
// consumer tile instead of once per lane (LDS traffic for gates 640KB -> ~64KB
// per block-step). Sync = R12 (sc1 publish -> padded flags -> acquire-inv ->
// plain cached q reads). sh_g unions with sh_part (disjoint lifetimes).
__global__ __launch_bounds__(NTHR) void rgcn_persist(
    const float* __restrict__ X, const float* __restrict__ Af,
    const float* __restrict__ Wih, const float* __restrict__ Whh,
    const float* __restrict__ Bias, const float* __restrict__ Wq,
    const float* __restrict__ Bq, const float* __restrict__ Wd,
    const float* __restrict__ Bd, float* __restrict__ Out,
    uint32_t* qP0, uint32_t* qP1, uint32_t* flags)
{
  extern __shared__ __align__(16) char smem[];
  unsigned short* afrag = (unsigned short*)smem;                 // [64kc][64ln][8] 65536
  unsigned short* whxT  = (unsigned short*)(smem + 65536);       // [256n][104k]    53248
  unsigned short* wqT   = (unsigned short*)(smem + 118784);      // [64n][72k]       9216
  float*          sh_g  = (float*)(smem + 128000);               // [16][260] fp32  16640
  f32x4*          sh_part = (f32x4*)(smem + 128000);             // union (16384)
  unsigned short* sh_hx = (unsigned short*)(smem + 144640);      // [16][104] bf16   3328
  unsigned short* sh_q  = (unsigned short*)(smem + 147968);      // [16][64] bf16    2048

  const int tid = threadIdx.x;
  const int w = tid >> 6;        // wave 0..15 (== node row for per-thread work)
  const int c = tid & 63;        // lane
  const int base = blockIdx.x * 16;
  const int m = c & 15, quad = c >> 4;

  // ---- one-time staging ----
  for (int i = tid; i < 256 * 104; i += NTHR) {            // [WhhT | WihT | 0]
    int n = i / 104, k = i - n * 104;
    float v = (k < 64) ? Whh[k * 256 + n] : (k < 80) ? Wih[(k - 64) * 256 + n] : 0.f;
    whxT[i] = f2bf(v);
  }
  for (int i = tid; i < 64 * 72; i += NTHR) {              // WqT (pad k 64..71 = 0)
    int n = i / 72, k = i - n * 72;
    wqT[i] = (k < 64) ? f2bf(Wq[k * 64 + n]) : (unsigned short)0;
  }
  for (int i = tid; i < 16 * NN; i += NTHR) {              // A -> MFMA A-frag layout
    int r = i >> 11, k = i & (NN - 1);
    afrag[(k >> 5) * 512 + (((k >> 3) & 3) * 16 + r) * 8 + (k & 7)] =
        f2bf(Af[(size_t)(base + r) * NN + k]);
  }
  for (int i = tid; i < 16 * 104; i += NTHR) sh_hx[i] = 0; // h=0, x below, pad=0
  __syncthreads();
  if (c < 16) sh_hx[w * 104 + 64 + c] = f2bf(X[(size_t)(base + w) * (TT * DD) + c]);
  sh_q[w * 64 + c] = f2bf(tanh_(Bq[c]));                   // q_0 = tanh(b_q)
  __syncthreads();

  const float b_i = Bias[c], b_f = Bias[64 + c], b_g = Bias[128 + c], b_o = Bias[192 + c];
  const float wdc = Wd[c], bdc = Bd[0];
  const float bqv = (w < 4) ? Bq[w * 16 + m] : 0.f;        // q-GEMM col bias
  const int nt = w & 3, kh = w >> 2;                       // phase B tile coords
  const unsigned short* afp = afrag + (kh * 16) * 512 + c * 8;

  float creg = 0.f, hreg = 0.f;

  auto publish_core = [&](uint32_t* qP, uint32_t flagval) {
    if (tid < 256) {                       // 4 lanes -> 32 contiguous B per column
      int col = tid >> 2, pr = tid & 3;
      uint32_t lo = (uint32_t)sh_q[(4 * pr + 0) * 64 + col] |
                    ((uint32_t)sh_q[(4 * pr + 1) * 64 + col] << 16);
      uint32_t hi = (uint32_t)sh_q[(4 * pr + 2) * 64 + col] |
                    ((uint32_t)sh_q[(4 * pr + 3) * 64 + col] << 16);
      unsigned long long v = (unsigned long long)lo | ((unsigned long long)hi << 32);
      __hip_atomic_store((unsigned long long*)(qP + (size_t)col * (NN / 2) + (base >> 1) + 2 * pr),
                         v, __ATOMIC_RELAXED, __HIP_MEMORY_SCOPE_AGENT);
    }
    __builtin_amdgcn_s_waitcnt(0);         // sc1 stores acked at coherence point
    asm volatile("" ::: "memory");
    __syncthreads();
    if (tid == 0)
      __hip_atomic_store(&flags[blockIdx.x * 16], flagval,   // 64B-padded flag
                         __ATOMIC_RELAXED, __HIP_MEMORY_SCOPE_AGENT);
  };

  publish_core(qP0, 1u);

  for (int t = 0; t < TT; ++t) {
    // ---- gates-GEMM: wave w owns n-tile w (cols 16w..16w+15), 3 k-chunks ----
    f32x4 dg = {0.f, 0.f, 0.f, 0.f};
    {
      const unsigned short* ar = sh_hx + m * 104 + quad * 8;
      const unsigned short* br = whxT + (w * 16 + m) * 104 + quad * 8;
      #pragma unroll
      for (int ch = 0; ch < 3; ++ch)
        dg = __builtin_amdgcn_mfma_f32_16x16x32_bf16(*(const bf16x8*)(ar + ch * 32),
                                                     *(const bf16x8*)(br + ch * 32), dg, 0, 0, 0);
    }
    #pragma unroll
    for (int r = 0; r < 4; ++r)            // D: row=quad*4+r, col=16w+m
      sh_g[(quad * 4 + r) * 260 + w * 16 + m] = dg[r];

    float xnext = 0.f;                     // prefetch x_{t+1}
    if (c < 16 && t < TT - 1)
      xnext = X[(size_t)(base + w) * (TT * DD) + (t + 1) * DD + c];
    __syncthreads();

    // ---- epilogue: thread (node=w, col=c) gathers 4 gate pre-acts ----
    float gi = sigmoid_(b_i + sh_g[w * 260 + c]);
    float gf = sigmoid_(b_f + sh_g[w * 260 + 64 + c]);
    float gg = tanh_  (b_g + sh_g[w * 260 + 128 + c]);
    float go = sigmoid_(b_o + sh_g[w * 260 + 192 + c]);

    // ---- wave0: wait q_t from all 128 blocks, then acquire-inv ----
    if (w == 0) {
      const uint32_t target = (uint32_t)(t + 1);
      for (;;) {
        uint32_t f0 = __hip_atomic_load(&flags[c * 16],        __ATOMIC_RELAXED, __HIP_MEMORY_SCOPE_AGENT);
        uint32_t f1 = __hip_atomic_load(&flags[(64 + c) * 16], __ATOMIC_RELAXED, __HIP_MEMORY_SCOPE_AGENT);
        if (__all((f0 >= target) && (f1 >= target))) break;
        __builtin_amdgcn_s_sleep(1);
      }
      __builtin_amdgcn_fence(__ATOMIC_ACQUIRE, "agent");   // s_waitcnt + buffer_inv
    }
    __syncthreads();                       // also orders sh_g reads before sh_part write

    // ---- phase B: Aq_t via MFMA; q read with plain cached 16B loads ----
    const unsigned short* qbase = (const unsigned short*)((t & 1) ? qP1 : qP0);
    const unsigned short* qrow = qbase + (size_t)(nt * 16 + m) * NN + kh * 512 + quad * 8;
    f32x4 acc = {0.f, 0.f, 0.f, 0.f};
    #pragma unroll
    for (int ch = 0; ch < 16; ++ch) {
      bf16x8 av = *(const bf16x8*)(afp + ch * 512);
      bf16x8 bv = *(const bf16x8*)(qrow + ch * 32);
      acc = __builtin_amdgcn_mfma_f32_16x16x32_bf16(av, bv, acc, 0, 0, 0);
    }
    sh_part[w * 64 + c] = acc;
    __syncthreads();

    // D layout: col=lane&15, row=(lane>>4)*4+reg. Thread (w,c): sum 4 K-quarters.
    const float* pf = (const float*)sh_part;
    float aqv = 0.f;
    #pragma unroll
    for (int kh2 = 0; kh2 < 4; ++kh2)
      aqv += pf[((kh2 * 4 + quad) * 64 + (w >> 2) * 16 + m) * 4 + (w & 3)];

    // ---- update + fused output projection (sc1 write-through Out) ----
    creg = gf * (creg + aqv) + gi * gg;
    hreg = go * tanh_(creg);
    float red = hreg * wdc;
    #pragma unroll
    for (int off = 32; off; off >>= 1) red += __shfl_xor(red, off);
    if (c == 0) {
      union { float f; uint32_t u; } o; o.f = red + bdc;
      __hip_atomic_store((uint32_t*)&Out[(size_t)(base + w) * TT + t], o.u,
                         __ATOMIC_RELAXED, __HIP_MEMORY_SCOPE_AGENT);
    }

    // ---- write h_t (bf16) + x_{t+1} into sh_hx for next gates / q GEMMs ----
    sh_hx[w * 104 + c] = f2bf(hreg);
    if (c < 16) sh_hx[w * 104 + 64 + c] = f2bf(xnext);
    __syncthreads();

    // ---- q-GEMM (waves 0..3): q_{t+1} = tanh(h_t @ WqT + bq) -> sh_q ----
    if (w < 4) {
      f32x4 dq = {0.f, 0.f, 0.f, 0.f};
      const unsigned short* ar = sh_hx + m * 104 + quad * 8;
      const unsigned short* br = wqT + (w * 16 + m) * 72 + quad * 8;
      #pragma unroll
      for (int k2 = 0; k2 < 2; ++k2)
        dq = __builtin_amdgcn_mfma_f32_16x16x32_bf16(*(const bf16x8*)(ar + k2 * 32),
                                                     *(const bf16x8*)(br + k2 * 32), dq, 0, 0, 0);
      #pragma unroll
      for (int r = 0; r < 4; ++r)          // D: row=quad*4+r (node), col=16w+m
        sh_q[(quad * 4 + r) * 64 + w * 16 + m] = f2bf(tanh_(dq[r] + bqv));
    }
    __syncthreads();

    if (t < TT - 1)
      publish_core((t & 1) ? qP0 : qP1, (uint32_t)(t + 2));
  }
}

extern "C" void kernel_launch(void* const* d_in, const int* in_sizes, int n_in,
                              void* d_out, int out_size, void* d_ws, size_t ws_size,
                              hipStream_t stream) {
  const float* X    = (const float*)d_in[0];
  const float* Af   = (const float*)d_in[1];
  const float* Wih  = (const float*)d_in[2];
  const float* Whh  = (const float*)d_in[3];
  const float* Bias = (const float*)d_in[4];
  const float* Wq   = (const float*)d_in[5];
  const float* Bq   = (const float*)d_in[6];
  const float* Wd   = (const float*)d_in[7];
  const float* Bd   = (const float*)d_in[8];
  float* Out = (float*)d_out;

  char* ws = (char*)d_ws;
  uint32_t* flags = (uint32_t*)ws;                         // 128 flags, 64B apart (8 KB)
  uint32_t* qP0   = (uint32_t*)(ws + 8192);                // 64*1024 u32 = 256 KB
  uint32_t* qP1   = (uint32_t*)(ws + 8192 + 262144);       // 256 KB

  hipFuncSetAttribute((const void*)rgcn_persist,
                      hipFuncAttributeMaxDynamicSharedMemorySize, SMEM_BYTES);
  hipMemsetAsync(ws, 0, 8192, stream);                     // zero flags (poisoned 0xAA!)
  hipLaunchKernelGGL(rgcn_persist, dim3(NBLK), dim3(NTHR), SMEM_BYTES, stream,
                     X, Af, Wih, Whh, Bias, Wq, Bq, Wd, Bd, Out, qP0, qP1, flags);
}